// Round 5
// baseline (2484.889 us; speedup 1.0000x reference)
//
#include <hip/hip_runtime.h>
#include <math.h>

namespace {

constexpr int NB = 4, NSPK = 2, NCHN = 6;
constexpr int LSIG = 64000;
constexpr int NFFT = 512, HOPSZ = 128, NFREQ = 257;
constexpr int NT = 505;               // frames
constexpr int TAPS = 20;
constexpr int NG = NB * NFREQ * NSPK; // 2056 systems
constexpr int NSIG = NB * NSPK * NCHN; // 48 istft signals
constexpr float PI_F = 3.14159265358979323846f;
constexpr double LAMBDA_REG = 2e-4;
constexpr float FCP_EPS_F = 1e-3f;
constexpr int G_ELEMS = NG * TAPS * NCHN; // 246720 floats (real part only)

constexpr size_t WS_ALIGN = 256;
constexpr size_t align_up(size_t x) { return (x + WS_ALIGN - 1) & ~(WS_ALIGN - 1); }

// ws byte offsets
constexpr size_t SPH_B  = 0;                                        // [8][257][505] float2
constexpr size_t SPH_SZ = (size_t)NB * NSPK * NFREQ * NT * 8;
constexpr size_t SPHT_B = align_up(SPH_B + SPH_SZ);                 // [8][505][257] float2
constexpr size_t MXS_B  = align_up(SPHT_B + SPH_SZ);                // [24][257][505] float2
constexpr size_t MXS_SZ = (size_t)NB * NCHN * NFREQ * NT * 8;
constexpr size_t POW_B  = align_up(MXS_B + MXS_SZ);                 // [4][257][505] float
constexpr size_t POW_SZ = (size_t)NB * NFREQ * NT * 4;
constexpr size_t MX_B   = align_up(POW_B + POW_SZ);                 // [4] float
constexpr size_t R_B    = align_up(MX_B + (size_t)NB * 4);          // [2056][400] double2
constexpr size_t R_SZ   = (size_t)NG * TAPS * TAPS * 16;
constexpr size_t P_B    = align_up(R_B + R_SZ);                     // [2056][120] double2
constexpr size_t P_SZ   = (size_t)NG * TAPS * NCHN * 16;
constexpr size_t GCT_B  = align_up(P_B + P_SZ);                     // [8][20][6][257] float2
constexpr size_t GCT_SZ = (size_t)NB * NSPK * TAPS * NCHN * NFREQ * 8;
constexpr size_t FRM_B  = align_up(GCT_B + GCT_SZ);                 // [48][505][512] float

// ---------------- STFT via literal rDFT (table-driven) ----------------
__global__ void stft_kernel(const float* __restrict__ ref, const float* __restrict__ mix,
                            float2* __restrict__ sph, float2* __restrict__ spht,
                            float2* __restrict__ mxs) {
  __shared__ float xw[NFFT];
  __shared__ float st[NFFT];
  int blk = blockIdx.x;
  int sig = blk / NT;
  int t = blk - sig * NT;
  int tid = threadIdx.x;
  bool is_ref = sig < NB * NSPK;
  int m = is_ref ? sig : (sig - NB * NSPK);
  const float* src = is_ref ? (ref + (size_t)m * LSIG) : (mix + (size_t)m * LSIG);

  for (int n = tid; n < NFFT; n += 256) {
    st[n] = sinf(2.0f * PI_F * (float)n / (float)NFFT);
    int g = t * HOPSZ + n - NFFT / 2;
    float v = (g >= 0 && g < LSIG) ? src[g] : 0.0f;
    xw[n] = v * sinf(PI_F * (float)n / (float)NFFT);
  }
  __syncthreads();

  // X[k] = sum_n xw[n] * exp(-2*pi*i*k*n/512); ph = (k*n) mod 512
  for (int k = tid; k < NFREQ; k += 256) {
    float ax = 0.0f, ay = 0.0f;
    int ph = 0;
    for (int n = 0; n < NFFT; ++n) {
      float x = xw[n];
      ax += x * st[(ph + NFFT / 4) & (NFFT - 1)];  // cos
      ay -= x * st[ph];                            // sin
      ph = (ph + k) & (NFFT - 1);
    }
    float2 v = make_float2(ax, ay);
    if (is_ref) {
      sph[((size_t)m * NFREQ + k) * NT + t] = v;
      spht[((size_t)m * NT + t) * NFREQ + k] = v;
    } else {
      mxs[((size_t)m * NFREQ + k) * NT + t] = v;
    }
  }
}

// ---------------- power ----------------
__global__ void power_kernel(const float2* __restrict__ mxs, float* __restrict__ power) {
  int i = blockIdx.x * 256 + threadIdx.x;
  if (i >= NB * NFREQ * NT) return;
  int b = i / (NFREQ * NT);
  int r = i - b * (NFREQ * NT);
  float acc = 0.0f;
#pragma unroll
  for (int c = 0; c < NCHN; ++c) {
    float2 v = mxs[(size_t)(b * NCHN + c) * NFREQ * NT + r];
    acc += v.x * v.x + v.y * v.y;
  }
  power[i] = acc * (1.0f / (float)NCHN);
}

// ---------------- per-batch max ----------------
__global__ void max_kernel(const float* __restrict__ power, float* __restrict__ mx) {
  int b = blockIdx.x;
  const float* p = power + (size_t)b * NFREQ * NT;
  float m = 0.0f;
  for (int i = threadIdx.x; i < NFREQ * NT; i += 256) m = fmaxf(m, p[i]);
#pragma unroll
  for (int off = 32; off > 0; off >>= 1) m = fmaxf(m, __shfl_down(m, off, 64));
  __shared__ float sm[4];
  int wave = threadIdx.x >> 6, lane = threadIdx.x & 63;
  if (lane == 0) sm[wave] = m;
  __syncthreads();
  if (threadIdx.x == 0) mx[b] = fmaxf(fmaxf(sm[0], sm[1]), fmaxf(sm[2], sm[3]));
}

// ---------------- R / P accumulation (fp64 accumulators) ----------------
__global__ void rp_kernel(const float2* __restrict__ sph, const float2* __restrict__ mxs,
                          const float* __restrict__ power, const float* __restrict__ mx,
                          double2* __restrict__ R, double2* __restrict__ P) {
  __shared__ float2 Ysh[NT];
  __shared__ float2 Msh[NCHN][NT];
  __shared__ float Wsh[NT];
  int g = blockIdx.x;
  int s = g & 1;
  int bf = g >> 1;
  int f = bf % NFREQ;
  int b = bf / NFREQ;
  int tid = threadIdx.x;

  const float2* yrow = sph + ((size_t)(b * NSPK + s) * NFREQ + f) * NT;
  const float* prow = power + ((size_t)b * NFREQ + f) * NT;
  float add = mx[b] * FCP_EPS_F + 1e-6f;
  for (int t = tid; t < NT; t += blockDim.x) {
    Ysh[t] = yrow[t];
    Wsh[t] = 1.0f / (prow[t] + add);
  }
  for (int i = tid; i < NCHN * NT; i += blockDim.x) {
    int c = i / NT, t = i - c * NT;
    Msh[c][t] = mxs[((size_t)(b * NCHN + c) * NFREQ + f) * NT + t];
  }
  __syncthreads();

  const double invT = 1.0 / (double)NT;
  if (tid < TAPS * TAPS) {
    int p = tid / TAPS, q = tid - p * TAPS;
    int t0 = (TAPS - 1) - min(p, q);
    double ax = 0.0, ay = 0.0;
    for (int t = t0; t < NT; ++t) {
      double w = (double)Wsh[t];
      float2 a = Ysh[t - (TAPS - 1) + p];
      float2 bb = Ysh[t - (TAPS - 1) + q];
      ax += w * ((double)a.x * bb.x + (double)a.y * bb.y);
      ay += w * ((double)a.y * bb.x - (double)a.x * bb.y);
    }
    R[(size_t)g * TAPS * TAPS + tid] = make_double2(ax * invT, ay * invT);
  } else if (tid < TAPS * TAPS + TAPS * NCHN) {
    int i = tid - TAPS * TAPS;
    int p = i / NCHN, c = i - p * NCHN;
    int t0 = (TAPS - 1) - p;
    double ax = 0.0, ay = 0.0;
    for (int t = t0; t < NT; ++t) {
      double w = (double)Wsh[t];
      float2 a = Ysh[t - (TAPS - 1) + p];
      float2 mv = Msh[c][t];
      ax += w * ((double)a.x * mv.x + (double)a.y * mv.y);
      ay += w * ((double)a.y * mv.x - (double)a.x * mv.y);
    }
    P[(size_t)g * TAPS * NCHN + i] = make_double2(ax * invT, ay * invT);
  }
}

// ---------------- LU solve with partial pivoting (complex128) ----------------
// Writes Re(conj G) = Re(G) as float32 to d_out[0:G_ELEMS]; full conj(G) to gct.
__global__ void solve_kernel(const double2* __restrict__ R, const double2* __restrict__ P,
                             float* __restrict__ gout, float2* __restrict__ gct) {
  __shared__ double2 A[TAPS][TAPS];
  __shared__ double2 Bm[TAPS][NCHN];
  __shared__ int piv;
  int g = blockIdx.x;
  int tid = threadIdx.x;
  int s = g & 1;
  int bf = g >> 1;
  int f = bf % NFREQ;
  int b = bf / NFREQ;
  int bs = b * NSPK + s;

  for (int i = tid; i < TAPS * TAPS; i += 64)
    A[i / TAPS][i % TAPS] = R[(size_t)g * TAPS * TAPS + i];
  for (int i = tid; i < TAPS * NCHN; i += 64)
    Bm[i / NCHN][i % NCHN] = P[(size_t)g * TAPS * NCHN + i];
  __syncthreads();
  if (tid < TAPS) A[tid][tid].x += LAMBDA_REG;
  __syncthreads();

  for (int k = 0; k < TAPS; ++k) {
    if (tid == 0) {
      int r = k;
      double best = fabs(A[k][k].x) + fabs(A[k][k].y);
      for (int i = k + 1; i < TAPS; ++i) {
        double v = fabs(A[i][k].x) + fabs(A[i][k].y);
        if (v > best) { best = v; r = i; }
      }
      piv = r;
    }
    __syncthreads();
    int r = piv;
    if (r != k) {
      if (tid < TAPS) {
        double2 tmp = A[k][tid]; A[k][tid] = A[r][tid]; A[r][tid] = tmp;
      } else if (tid < TAPS + NCHN) {
        int c = tid - TAPS;
        double2 tmp = Bm[k][c]; Bm[k][c] = Bm[r][c]; Bm[r][c] = tmp;
      }
    }
    __syncthreads();
    double2 akk = A[k][k];
    double den = akk.x * akk.x + akk.y * akk.y;
    if (tid > k && tid < TAPS) {
      double2 a = A[tid][k];  // a / akk = a*conj(akk)/den
      A[tid][k] = make_double2((a.x * akk.x + a.y * akk.y) / den,
                               (a.y * akk.x - a.x * akk.y) / den);
    }
    __syncthreads();
    int nr = TAPS - 1 - k;
    int nc = nr + NCHN;  // trailing A cols + B cols
    for (int idx = tid; idx < nr * nc; idx += 64) {
      int i = k + 1 + idx / nc;
      int jj = idx % nc;
      double2 mlt = A[i][k];
      if (jj < nr) {
        int j = k + 1 + jj;
        double2 u = A[k][j];
        A[i][j].x -= mlt.x * u.x - mlt.y * u.y;
        A[i][j].y -= mlt.x * u.y + mlt.y * u.x;
      } else {
        int c = jj - nr;
        double2 u = Bm[k][c];
        Bm[i][c].x -= mlt.x * u.x - mlt.y * u.y;
        Bm[i][c].y -= mlt.x * u.y + mlt.y * u.x;
      }
    }
    __syncthreads();
  }

  // back substitution U x = y
  if (tid < NCHN) {
    int c = tid;
    for (int k = TAPS - 1; k >= 0; --k) {
      double sx = Bm[k][c].x, sy = Bm[k][c].y;
      for (int j = k + 1; j < TAPS; ++j) {
        double2 u = A[k][j], xv = Bm[j][c];
        sx -= u.x * xv.x - u.y * xv.y;
        sy -= u.x * xv.y + u.y * xv.x;
      }
      double2 akk = A[k][k];
      double den = akk.x * akk.x + akk.y * akk.y;
      Bm[k][c] = make_double2((sx * akk.x + sy * akk.y) / den,
                              (sy * akk.x - sx * akk.y) / den);
    }
  }
  __syncthreads();

  for (int i = tid; i < TAPS * NCHN; i += 64) {
    int p = i / NCHN, c = i - p * NCHN;
    double2 gv = Bm[p][c];
    float gx = (float)gv.x, gy = (float)(-gv.y);  // conj(G)
    gout[(size_t)g * TAPS * NCHN + i] = gx;       // float32, real part only
    gct[(((size_t)bs * TAPS + p) * NCHN + c) * NFREQ + f] = make_float2(gx, gy);
  }
}

// ---------------- ret + literal inverse rDFT ----------------
__global__ void ret_ifft_kernel(const float2* __restrict__ spht, const float2* __restrict__ gct,
                                float* __restrict__ frames) {
  __shared__ float2 spec[NFREQ];
  __shared__ float st[NFFT];
  int blk = blockIdx.x;
  int t = blk % NT;
  int sc = blk / NT;
  int c = sc % NCHN;
  int bs = sc / NCHN;
  int tid = threadIdx.x;

  for (int n = tid; n < NFFT; n += 256)
    st[n] = sinf(2.0f * PI_F * (float)n / (float)NFFT);

  int p0 = max(0, (TAPS - 1) - t);
  for (int f = tid; f < NFREQ; f += 256) {
    float sx = 0.0f, sy = 0.0f;
    for (int p = p0; p < TAPS; ++p) {
      float2 y = spht[((size_t)bs * NT + (t - (TAPS - 1) + p)) * NFREQ + f];
      float2 gc = gct[(((size_t)bs * TAPS + p) * NCHN + c) * NFREQ + f];
      sx += y.x * gc.x - y.y * gc.y;
      sy += y.x * gc.y + y.y * gc.x;
    }
    spec[f] = make_float2(sx, sy);
  }
  __syncthreads();

  float* frow = frames + ((size_t)sc * NT + t) * NFFT;
  for (int n = tid; n < NFFT; n += 256) {
    float acc = spec[0].x + ((n & 1) ? -spec[NFFT / 2].x : spec[NFFT / 2].x);
    int ph = 0;
    for (int k = 1; k < NFFT / 2; ++k) {
      ph = (ph + n) & (NFFT - 1);  // ph = k*n mod 512
      acc += 2.0f * (spec[k].x * st[(ph + NFFT / 4) & (NFFT - 1)] - spec[k].y * st[ph]);
    }
    float w = sinf(PI_F * (float)n / (float)NFFT);
    frow[n] = acc * (1.0f / (float)NFFT) * w;
  }
}

// ---------------- overlap-add + env normalize + crop (float32 out) ----------------
__global__ void ola_kernel(const float* __restrict__ frames, float* __restrict__ out) {
  int i = blockIdx.x * 256 + threadIdx.x;
  if (i >= NSIG * LSIG) return;
  int sig = i / LSIG;
  int l = i - sig * LSIG;
  int lp = l + NFFT / 2;
  int j0 = max(0, (lp - (NFFT - HOPSZ)) / HOPSZ);
  int j1 = min(NT - 1, lp / HOPSZ);
  float acc = 0.0f, env = 0.0f;
  for (int j = j0; j <= j1; ++j) {
    int n = lp - j * HOPSZ;
    acc += frames[((size_t)sig * NT + j) * NFFT + n];
    float w = sinf(PI_F * (float)n / (float)NFFT);
    env += w * w;
  }
  out[(size_t)G_ELEMS + i] = acc / (env > 1e-11f ? env : 1.0f);
}

}  // namespace

extern "C" void kernel_launch(void* const* d_in, const int* in_sizes, int n_in,
                              void* d_out, int out_size, void* d_ws, size_t ws_size,
                              hipStream_t stream) {
  const float* ref = (const float*)d_in[0];
  const float* mix = (const float*)d_in[1];
  if (n_in >= 2 && in_sizes[0] > in_sizes[1]) {
    const float* tmp = ref; ref = mix; mix = tmp;
  }
  char* ws = (char*)d_ws;

  float2*  sph   = (float2*)(ws + SPH_B);
  float2*  spht  = (float2*)(ws + SPHT_B);
  float2*  mxs   = (float2*)(ws + MXS_B);
  float*   power = (float*)(ws + POW_B);
  float*   mx    = (float*)(ws + MX_B);
  double2* R     = (double2*)(ws + R_B);
  double2* P     = (double2*)(ws + P_B);
  float2*  gct   = (float2*)(ws + GCT_B);
  float*   frames= (float*)(ws + FRM_B);
  float*   out   = (float*)d_out;

  stft_kernel<<<dim3((NB * NSPK + NB * NCHN) * NT), dim3(256), 0, stream>>>(ref, mix, sph, spht, mxs);
  power_kernel<<<dim3((NB * NFREQ * NT + 255) / 256), dim3(256), 0, stream>>>(mxs, power);
  max_kernel<<<dim3(NB), dim3(256), 0, stream>>>(power, mx);
  rp_kernel<<<dim3(NG), dim3(576), 0, stream>>>(sph, mxs, power, mx, R, P);
  solve_kernel<<<dim3(NG), dim3(64), 0, stream>>>(R, P, out, gct);
  ret_ifft_kernel<<<dim3(NSIG * NT), dim3(256), 0, stream>>>(spht, gct, frames);
  ola_kernel<<<dim3((NSIG * LSIG + 255) / 256), dim3(256), 0, stream>>>(frames, out);
}

// Round 6
// 698.494 us; speedup vs baseline: 3.5575x; 3.5575x over previous
//
#include <hip/hip_runtime.h>
#include <math.h>

namespace {

constexpr int NB = 4, NSPK = 2, NCHN = 6;
constexpr int LSIG = 64000;
constexpr int NFFT = 512, HOPSZ = 128, NFREQ = 257;
constexpr int NT = 505;               // frames
constexpr int TAPS = 20;
constexpr int NG = NB * NFREQ * NSPK; // 2056 systems
constexpr int NSIG = NB * NSPK * NCHN; // 48 istft signals
constexpr float PI_F = 3.14159265358979323846f;
constexpr double LAMBDA_REG = 2e-4;
constexpr float FCP_EPS_F = 1e-3f;
constexpr int G_ELEMS = NG * TAPS * NCHN; // 246720 floats (real part only)

constexpr size_t WS_ALIGN = 256;
constexpr size_t align_up(size_t x) { return (x + WS_ALIGN - 1) & ~(WS_ALIGN - 1); }

// ws byte offsets
constexpr size_t SPH_B  = 0;                                        // [8][257][505] float2
constexpr size_t SPH_SZ = (size_t)NB * NSPK * NFREQ * NT * 8;
constexpr size_t SPHT_B = align_up(SPH_B + SPH_SZ);                 // [8][505][257] float2
constexpr size_t MXS_B  = align_up(SPHT_B + SPH_SZ);                // [24][257][505] float2
constexpr size_t MXS_SZ = (size_t)NB * NCHN * NFREQ * NT * 8;
constexpr size_t POW_B  = align_up(MXS_B + MXS_SZ);                 // [4][257][505] float
constexpr size_t POW_SZ = (size_t)NB * NFREQ * NT * 4;
constexpr size_t MX_B   = align_up(POW_B + POW_SZ);                 // [4] float
constexpr size_t R_B    = align_up(MX_B + (size_t)NB * 4);          // [2056][400] double2
constexpr size_t R_SZ   = (size_t)NG * TAPS * TAPS * 16;
constexpr size_t P_B    = align_up(R_B + R_SZ);                     // [2056][120] double2
constexpr size_t P_SZ   = (size_t)NG * TAPS * NCHN * 16;
constexpr size_t GCT_B  = align_up(P_B + P_SZ);                     // [8][20][6][257] float2
constexpr size_t GCT_SZ = (size_t)NB * NSPK * TAPS * NCHN * NFREQ * 8;
constexpr size_t FRM_B  = align_up(GCT_B + GCT_SZ);                 // [48][505][512] float

__device__ __forceinline__ int rev9(int n) { return (int)(__brev((unsigned)n) >> 23); }

// In-LDS radix-2 DIT FFT, 512 points, 256 threads, input pre-bit-reversed.
// sign = -1 forward, +1 inverse (unscaled). Validated: round-1 (this FFT) and
// round-2 (literal DFT) pipelines produced bit-identical outputs.
__device__ __forceinline__ void fft512(float2* buf, int tid, float sign) {
#pragma unroll
  for (int s = 1; s <= 9; ++s) {
    int half = 1 << (s - 1);
    int blk = tid >> (s - 1);
    int pos = tid & (half - 1);
    int i0 = (blk << s) + pos;
    int i1 = i0 + half;
    float ang = sign * 2.0f * PI_F * (float)pos / (float)(half << 1);
    float sn, cs;
    __sincosf(ang, &sn, &cs);
    float2 u = buf[i0];
    float2 v = buf[i1];
    float2 vw = make_float2(v.x * cs - v.y * sn, v.x * sn + v.y * cs);
    buf[i0] = make_float2(u.x + vw.x, u.y + vw.y);
    buf[i1] = make_float2(u.x - vw.x, u.y - vw.y);
    __syncthreads();
  }
}

// ---------------- STFT (radix-2 FFT) ----------------
// grid: (8 + 24) * NT blocks, 256 threads
__global__ void stft_kernel(const float* __restrict__ ref, const float* __restrict__ mix,
                            float2* __restrict__ sph, float2* __restrict__ spht,
                            float2* __restrict__ mxs) {
  __shared__ float2 buf[NFFT];
  int blk = blockIdx.x;
  int sig = blk / NT;
  int t = blk - sig * NT;
  int tid = threadIdx.x;
  bool is_ref = sig < NB * NSPK;
  int m = is_ref ? sig : (sig - NB * NSPK);
  const float* src = is_ref ? (ref + (size_t)m * LSIG) : (mix + (size_t)m * LSIG);

  for (int n = tid; n < NFFT; n += 256) {
    int g = t * HOPSZ + n - NFFT / 2;
    float v = (g >= 0 && g < LSIG) ? src[g] : 0.0f;
    float w = sinf(PI_F * (float)n / (float)NFFT);  // sqrt-hann
    buf[rev9(n)] = make_float2(v * w, 0.0f);
  }
  __syncthreads();
  fft512(buf, tid, -1.0f);

  if (is_ref) {
    float2* d1 = sph + (size_t)m * NFREQ * NT;
    float2* d2 = spht + ((size_t)m * NT + t) * NFREQ;
    for (int f = tid; f < NFREQ; f += 256) {
      float2 v = buf[f];
      d1[(size_t)f * NT + t] = v;
      d2[f] = v;
    }
  } else {
    float2* d1 = mxs + (size_t)m * NFREQ * NT;
    for (int f = tid; f < NFREQ; f += 256) d1[(size_t)f * NT + t] = buf[f];
  }
}

// ---------------- power ----------------
__global__ void power_kernel(const float2* __restrict__ mxs, float* __restrict__ power) {
  int i = blockIdx.x * 256 + threadIdx.x;
  if (i >= NB * NFREQ * NT) return;
  int b = i / (NFREQ * NT);
  int r = i - b * (NFREQ * NT);
  float acc = 0.0f;
#pragma unroll
  for (int c = 0; c < NCHN; ++c) {
    float2 v = mxs[(size_t)(b * NCHN + c) * NFREQ * NT + r];
    acc += v.x * v.x + v.y * v.y;
  }
  power[i] = acc * (1.0f / (float)NCHN);
}

// ---------------- per-batch max ----------------
__global__ void max_kernel(const float* __restrict__ power, float* __restrict__ mx) {
  int b = blockIdx.x;
  const float* p = power + (size_t)b * NFREQ * NT;
  float m = 0.0f;
  for (int i = threadIdx.x; i < NFREQ * NT; i += 256) m = fmaxf(m, p[i]);
#pragma unroll
  for (int off = 32; off > 0; off >>= 1) m = fmaxf(m, __shfl_down(m, off, 64));
  __shared__ float sm[4];
  int wave = threadIdx.x >> 6, lane = threadIdx.x & 63;
  if (lane == 0) sm[wave] = m;
  __syncthreads();
  if (threadIdx.x == 0) mx[b] = fmaxf(fmaxf(sm[0], sm[1]), fmaxf(sm[2], sm[3]));
}

// ---------------- R / P accumulation (fp64 accumulators) ----------------
__global__ void rp_kernel(const float2* __restrict__ sph, const float2* __restrict__ mxs,
                          const float* __restrict__ power, const float* __restrict__ mx,
                          double2* __restrict__ R, double2* __restrict__ P) {
  __shared__ float2 Ysh[NT];
  __shared__ float2 Msh[NCHN][NT];
  __shared__ float Wsh[NT];
  int g = blockIdx.x;
  int s = g & 1;
  int bf = g >> 1;
  int f = bf % NFREQ;
  int b = bf / NFREQ;
  int tid = threadIdx.x;

  const float2* yrow = sph + ((size_t)(b * NSPK + s) * NFREQ + f) * NT;
  const float* prow = power + ((size_t)b * NFREQ + f) * NT;
  float add = mx[b] * FCP_EPS_F + 1e-6f;
  for (int t = tid; t < NT; t += blockDim.x) {
    Ysh[t] = yrow[t];
    Wsh[t] = 1.0f / (prow[t] + add);
  }
  for (int i = tid; i < NCHN * NT; i += blockDim.x) {
    int c = i / NT, t = i - c * NT;
    Msh[c][t] = mxs[((size_t)(b * NCHN + c) * NFREQ + f) * NT + t];
  }
  __syncthreads();

  const double invT = 1.0 / (double)NT;
  if (tid < TAPS * TAPS) {
    int p = tid / TAPS, q = tid - p * TAPS;
    int t0 = (TAPS - 1) - min(p, q);
    double ax = 0.0, ay = 0.0;
    for (int t = t0; t < NT; ++t) {
      double w = (double)Wsh[t];
      float2 a = Ysh[t - (TAPS - 1) + p];
      float2 bb = Ysh[t - (TAPS - 1) + q];
      ax += w * ((double)a.x * bb.x + (double)a.y * bb.y);
      ay += w * ((double)a.y * bb.x - (double)a.x * bb.y);
    }
    R[(size_t)g * TAPS * TAPS + tid] = make_double2(ax * invT, ay * invT);
  } else if (tid < TAPS * TAPS + TAPS * NCHN) {
    int i = tid - TAPS * TAPS;
    int p = i / NCHN, c = i - p * NCHN;
    int t0 = (TAPS - 1) - p;
    double ax = 0.0, ay = 0.0;
    for (int t = t0; t < NT; ++t) {
      double w = (double)Wsh[t];
      float2 a = Ysh[t - (TAPS - 1) + p];
      float2 mv = Msh[c][t];
      ax += w * ((double)a.x * mv.x + (double)a.y * mv.y);
      ay += w * ((double)a.y * mv.x - (double)a.x * mv.y);
    }
    P[(size_t)g * TAPS * NCHN + i] = make_double2(ax * invT, ay * invT);
  }
}

// ---------------- LU solve with partial pivoting (complex128) ----------------
// Writes Re(conj G) = Re(G) as float32 to d_out[0:G_ELEMS]; full conj(G) to gct.
__global__ void solve_kernel(const double2* __restrict__ R, const double2* __restrict__ P,
                             float* __restrict__ gout, float2* __restrict__ gct) {
  __shared__ double2 A[TAPS][TAPS];
  __shared__ double2 Bm[TAPS][NCHN];
  __shared__ int piv;
  int g = blockIdx.x;
  int tid = threadIdx.x;
  int s = g & 1;
  int bf = g >> 1;
  int f = bf % NFREQ;
  int b = bf / NFREQ;
  int bs = b * NSPK + s;

  for (int i = tid; i < TAPS * TAPS; i += 64)
    A[i / TAPS][i % TAPS] = R[(size_t)g * TAPS * TAPS + i];
  for (int i = tid; i < TAPS * NCHN; i += 64)
    Bm[i / NCHN][i % NCHN] = P[(size_t)g * TAPS * NCHN + i];
  __syncthreads();
  if (tid < TAPS) A[tid][tid].x += LAMBDA_REG;
  __syncthreads();

  for (int k = 0; k < TAPS; ++k) {
    if (tid == 0) {
      int r = k;
      double best = fabs(A[k][k].x) + fabs(A[k][k].y);
      for (int i = k + 1; i < TAPS; ++i) {
        double v = fabs(A[i][k].x) + fabs(A[i][k].y);
        if (v > best) { best = v; r = i; }
      }
      piv = r;
    }
    __syncthreads();
    int r = piv;
    if (r != k) {
      if (tid < TAPS) {
        double2 tmp = A[k][tid]; A[k][tid] = A[r][tid]; A[r][tid] = tmp;
      } else if (tid < TAPS + NCHN) {
        int c = tid - TAPS;
        double2 tmp = Bm[k][c]; Bm[k][c] = Bm[r][c]; Bm[r][c] = tmp;
      }
    }
    __syncthreads();
    double2 akk = A[k][k];
    double den = akk.x * akk.x + akk.y * akk.y;
    if (tid > k && tid < TAPS) {
      double2 a = A[tid][k];  // a / akk = a*conj(akk)/den
      A[tid][k] = make_double2((a.x * akk.x + a.y * akk.y) / den,
                               (a.y * akk.x - a.x * akk.y) / den);
    }
    __syncthreads();
    int nr = TAPS - 1 - k;
    int nc = nr + NCHN;  // trailing A cols + B cols
    for (int idx = tid; idx < nr * nc; idx += 64) {
      int i = k + 1 + idx / nc;
      int jj = idx % nc;
      double2 mlt = A[i][k];
      if (jj < nr) {
        int j = k + 1 + jj;
        double2 u = A[k][j];
        A[i][j].x -= mlt.x * u.x - mlt.y * u.y;
        A[i][j].y -= mlt.x * u.y + mlt.y * u.x;
      } else {
        int c = jj - nr;
        double2 u = Bm[k][c];
        Bm[i][c].x -= mlt.x * u.x - mlt.y * u.y;
        Bm[i][c].y -= mlt.x * u.y + mlt.y * u.x;
      }
    }
    __syncthreads();
  }

  // back substitution U x = y
  if (tid < NCHN) {
    int c = tid;
    for (int k = TAPS - 1; k >= 0; --k) {
      double sx = Bm[k][c].x, sy = Bm[k][c].y;
      for (int j = k + 1; j < TAPS; ++j) {
        double2 u = A[k][j], xv = Bm[j][c];
        sx -= u.x * xv.x - u.y * xv.y;
        sy -= u.x * xv.y + u.y * xv.x;
      }
      double2 akk = A[k][k];
      double den = akk.x * akk.x + akk.y * akk.y;
      Bm[k][c] = make_double2((sx * akk.x + sy * akk.y) / den,
                              (sy * akk.x - sx * akk.y) / den);
    }
  }
  __syncthreads();

  for (int i = tid; i < TAPS * NCHN; i += 64) {
    int p = i / NCHN, c = i - p * NCHN;
    double2 gv = Bm[p][c];
    float gx = (float)gv.x, gy = (float)(-gv.y);  // conj(G)
    gout[(size_t)g * TAPS * NCHN + i] = gx;       // float32, real part only
    gct[(((size_t)bs * TAPS + p) * NCHN + c) * NFREQ + f] = make_float2(gx, gy);
  }
}

// ---------------- ret + inverse FFT (radix-2) ----------------
// grid: NSIG*NT blocks, 256 threads. blk = sc*NT + t, sc = (b*2+s)*6+c
__global__ void ret_ifft_kernel(const float2* __restrict__ spht, const float2* __restrict__ gct,
                                float* __restrict__ frames) {
  __shared__ float2 spec[NFREQ];
  __shared__ float2 buf[NFFT];
  int blk = blockIdx.x;
  int t = blk % NT;
  int sc = blk / NT;
  int c = sc % NCHN;
  int bs = sc / NCHN;
  int tid = threadIdx.x;

  int p0 = max(0, (TAPS - 1) - t);
  for (int f = tid; f < NFREQ; f += 256) {
    float sx = 0.0f, sy = 0.0f;
    for (int p = p0; p < TAPS; ++p) {
      float2 y = spht[((size_t)bs * NT + (t - (TAPS - 1) + p)) * NFREQ + f];
      float2 gc = gct[(((size_t)bs * TAPS + p) * NCHN + c) * NFREQ + f];
      sx += y.x * gc.x - y.y * gc.y;
      sy += y.x * gc.y + y.y * gc.x;
    }
    spec[f] = make_float2(sx, sy);
  }
  __syncthreads();
  // Hermitian extension into bit-reversed positions
  for (int k = tid; k < NFFT; k += 256) {
    float2 v;
    if (k <= NFFT / 2) v = spec[k];
    else {
      float2 u = spec[NFFT - k];
      v = make_float2(u.x, -u.y);
    }
    buf[rev9(k)] = v;
  }
  __syncthreads();
  fft512(buf, tid, +1.0f);

  float* frow = frames + ((size_t)sc * NT + t) * NFFT;
  for (int n = tid; n < NFFT; n += 256) {
    float w = sinf(PI_F * (float)n / (float)NFFT);
    frow[n] = buf[n].x * (1.0f / (float)NFFT) * w;
  }
}

// ---------------- overlap-add + env normalize + crop (float32 out) ----------------
__global__ void ola_kernel(const float* __restrict__ frames, float* __restrict__ out) {
  int i = blockIdx.x * 256 + threadIdx.x;
  if (i >= NSIG * LSIG) return;
  int sig = i / LSIG;
  int l = i - sig * LSIG;
  int lp = l + NFFT / 2;
  int j0 = max(0, (lp - (NFFT - HOPSZ)) / HOPSZ);
  int j1 = min(NT - 1, lp / HOPSZ);
  float acc = 0.0f, env = 0.0f;
  for (int j = j0; j <= j1; ++j) {
    int n = lp - j * HOPSZ;
    acc += frames[((size_t)sig * NT + j) * NFFT + n];
    float w = sinf(PI_F * (float)n / (float)NFFT);
    env += w * w;
  }
  out[(size_t)G_ELEMS + i] = acc / (env > 1e-11f ? env : 1.0f);
}

}  // namespace

extern "C" void kernel_launch(void* const* d_in, const int* in_sizes, int n_in,
                              void* d_out, int out_size, void* d_ws, size_t ws_size,
                              hipStream_t stream) {
  const float* ref = (const float*)d_in[0];
  const float* mix = (const float*)d_in[1];
  if (n_in >= 2 && in_sizes[0] > in_sizes[1]) {
    const float* tmp = ref; ref = mix; mix = tmp;
  }
  char* ws = (char*)d_ws;

  float2*  sph   = (float2*)(ws + SPH_B);
  float2*  spht  = (float2*)(ws + SPHT_B);
  float2*  mxs   = (float2*)(ws + MXS_B);
  float*   power = (float*)(ws + POW_B);
  float*   mx    = (float*)(ws + MX_B);
  double2* R     = (double2*)(ws + R_B);
  double2* P     = (double2*)(ws + P_B);
  float2*  gct   = (float2*)(ws + GCT_B);
  float*   frames= (float*)(ws + FRM_B);
  float*   out   = (float*)d_out;

  stft_kernel<<<dim3((NB * NSPK + NB * NCHN) * NT), dim3(256), 0, stream>>>(ref, mix, sph, spht, mxs);
  power_kernel<<<dim3((NB * NFREQ * NT + 255) / 256), dim3(256), 0, stream>>>(mxs, power);
  max_kernel<<<dim3(NB), dim3(256), 0, stream>>>(power, mx);
  rp_kernel<<<dim3(NG), dim3(576), 0, stream>>>(sph, mxs, power, mx, R, P);
  solve_kernel<<<dim3(NG), dim3(64), 0, stream>>>(R, P, out, gct);
  ret_ifft_kernel<<<dim3(NSIG * NT), dim3(256), 0, stream>>>(spht, gct, frames);
  ola_kernel<<<dim3((NSIG * LSIG + 255) / 256), dim3(256), 0, stream>>>(frames, out);
}

// Round 7
// 652.924 us; speedup vs baseline: 3.8058x; 1.0698x over previous
//
#include <hip/hip_runtime.h>
#include <math.h>

namespace {

constexpr int NB = 4, NSPK = 2, NCHN = 6;
constexpr int LSIG = 64000;
constexpr int NFFT = 512, HOPSZ = 128, NFREQ = 257;
constexpr int NT = 505;               // frames
constexpr int TAPS = 20;
constexpr int NG = NB * NFREQ * NSPK; // 2056 systems
constexpr int NSIG = NB * NSPK * NCHN; // 48 istft signals
constexpr float PI_F = 3.14159265358979323846f;
constexpr double LAMBDA_REG = 2e-4;
constexpr float FCP_EPS_F = 1e-3f;
constexpr int G_ELEMS = NG * TAPS * NCHN; // 246720 floats (real part only)
constexpr int TCHUNK = 5;             // 505 = 5 * 101
constexpr int NCHUNK = NT / TCHUNK;   // 101

constexpr size_t WS_ALIGN = 256;
constexpr size_t align_up(size_t x) { return (x + WS_ALIGN - 1) & ~(WS_ALIGN - 1); }

// ws byte offsets
constexpr size_t SPH_B  = 0;                                        // [8][257][505] float2
constexpr size_t SPH_SZ = (size_t)NB * NSPK * NFREQ * NT * 8;
constexpr size_t SPHT_B = align_up(SPH_B + SPH_SZ);                 // [8][505][257] float2
constexpr size_t MXS_B  = align_up(SPHT_B + SPH_SZ);                // [24][257][505] float2
constexpr size_t MXS_SZ = (size_t)NB * NCHN * NFREQ * NT * 8;
constexpr size_t POW_B  = align_up(MXS_B + MXS_SZ);                 // [4][257][505] float
constexpr size_t POW_SZ = (size_t)NB * NFREQ * NT * 4;
constexpr size_t MX_B   = align_up(POW_B + POW_SZ);                 // [4] float
constexpr size_t R_B    = align_up(MX_B + (size_t)NB * 4);          // [2056][400] float2
constexpr size_t R_SZ   = (size_t)NG * TAPS * TAPS * 8;
constexpr size_t P_B    = align_up(R_B + R_SZ);                     // [2056][120] float2
constexpr size_t P_SZ   = (size_t)NG * TAPS * NCHN * 8;
constexpr size_t GCT_B  = align_up(P_B + P_SZ);                     // [8][20][6][257] float2
constexpr size_t GCT_SZ = (size_t)NB * NSPK * TAPS * NCHN * NFREQ * 8;
constexpr size_t FRM_B  = align_up(GCT_B + GCT_SZ);                 // [48][505][512] float

__device__ __forceinline__ int rev9(int n) { return (int)(__brev((unsigned)n) >> 23); }

// In-LDS radix-2 DIT FFT, 512 points, 256 threads, input pre-bit-reversed.
// sign = -1 forward, +1 inverse (unscaled). HW-validated (r1 vs r2 bit-identical).
__device__ __forceinline__ void fft512(float2* buf, int tid, float sign) {
#pragma unroll
  for (int s = 1; s <= 9; ++s) {
    int half = 1 << (s - 1);
    int blk = tid >> (s - 1);
    int pos = tid & (half - 1);
    int i0 = (blk << s) + pos;
    int i1 = i0 + half;
    float ang = sign * 2.0f * PI_F * (float)pos / (float)(half << 1);
    float sn, cs;
    __sincosf(ang, &sn, &cs);
    float2 u = buf[i0];
    float2 v = buf[i1];
    float2 vw = make_float2(v.x * cs - v.y * sn, v.x * sn + v.y * cs);
    buf[i0] = make_float2(u.x + vw.x, u.y + vw.y);
    buf[i1] = make_float2(u.x - vw.x, u.y - vw.y);
    __syncthreads();
  }
}

// ---------------- STFT (radix-2 FFT) ----------------
// grid: (8 + 24) * NT blocks, 256 threads
__global__ void stft_kernel(const float* __restrict__ ref, const float* __restrict__ mix,
                            float2* __restrict__ sph, float2* __restrict__ spht,
                            float2* __restrict__ mxs) {
  __shared__ float2 buf[NFFT];
  int blk = blockIdx.x;
  int sig = blk / NT;
  int t = blk - sig * NT;
  int tid = threadIdx.x;
  bool is_ref = sig < NB * NSPK;
  int m = is_ref ? sig : (sig - NB * NSPK);
  const float* src = is_ref ? (ref + (size_t)m * LSIG) : (mix + (size_t)m * LSIG);

  for (int n = tid; n < NFFT; n += 256) {
    int g = t * HOPSZ + n - NFFT / 2;
    float v = (g >= 0 && g < LSIG) ? src[g] : 0.0f;
    float w = sinf(PI_F * (float)n / (float)NFFT);  // sqrt-hann
    buf[rev9(n)] = make_float2(v * w, 0.0f);
  }
  __syncthreads();
  fft512(buf, tid, -1.0f);

  if (is_ref) {
    float2* d1 = sph + (size_t)m * NFREQ * NT;
    float2* d2 = spht + ((size_t)m * NT + t) * NFREQ;
    for (int f = tid; f < NFREQ; f += 256) {
      float2 v = buf[f];
      d1[(size_t)f * NT + t] = v;
      d2[f] = v;
    }
  } else {
    float2* d1 = mxs + (size_t)m * NFREQ * NT;
    for (int f = tid; f < NFREQ; f += 256) d1[(size_t)f * NT + t] = buf[f];
  }
}

// ---------------- power ----------------
__global__ void power_kernel(const float2* __restrict__ mxs, float* __restrict__ power) {
  int i = blockIdx.x * 256 + threadIdx.x;
  if (i >= NB * NFREQ * NT) return;
  int b = i / (NFREQ * NT);
  int r = i - b * (NFREQ * NT);
  float acc = 0.0f;
#pragma unroll
  for (int c = 0; c < NCHN; ++c) {
    float2 v = mxs[(size_t)(b * NCHN + c) * NFREQ * NT + r];
    acc += v.x * v.x + v.y * v.y;
  }
  power[i] = acc * (1.0f / (float)NCHN);
}

// ---------------- per-batch max ----------------
__global__ void max_kernel(const float* __restrict__ power, float* __restrict__ mx) {
  int b = blockIdx.x;
  const float* p = power + (size_t)b * NFREQ * NT;
  float m = 0.0f;
  for (int i = threadIdx.x; i < NFREQ * NT; i += 256) m = fmaxf(m, p[i]);
#pragma unroll
  for (int off = 32; off > 0; off >>= 1) m = fmaxf(m, __shfl_down(m, off, 64));
  __shared__ float sm[4];
  int wave = threadIdx.x >> 6, lane = threadIdx.x & 63;
  if (lane == 0) sm[wave] = m;
  __syncthreads();
  if (threadIdx.x == 0) mx[b] = fmaxf(fmaxf(sm[0], sm[1]), fmaxf(sm[2], sm[3]));
}

// ---------------- R / P accumulation (fp32, Hermitian R) ----------------
// grid: NG blocks, 384 threads (6 waves). Waves 0-3: 210 R-threads (lower tri).
// Waves 4-5: 120 P-threads. Matches reference's float32 einsum arithmetic.
__global__ void rp_kernel(const float2* __restrict__ sph, const float2* __restrict__ mxs,
                          const float* __restrict__ power, const float* __restrict__ mx,
                          float2* __restrict__ R, float2* __restrict__ P) {
  __shared__ float2 Ysh[NT];
  __shared__ float2 MWsh[NCHN][NT];   // w[t] * conj(M[c][t])
  __shared__ float Wsh[NT];
  int g = blockIdx.x;
  int s = g & 1;
  int bf = g >> 1;
  int f = bf % NFREQ;
  int b = bf / NFREQ;
  int tid = threadIdx.x;

  const float2* yrow = sph + ((size_t)(b * NSPK + s) * NFREQ + f) * NT;
  const float* prow = power + ((size_t)b * NFREQ + f) * NT;
  float add = mx[b] * FCP_EPS_F + 1e-6f;
  for (int t = tid; t < NT; t += 384) {
    Wsh[t] = 1.0f / (prow[t] + add);
    Ysh[t] = yrow[t];
  }
  __syncthreads();
  for (int i = tid; i < NCHN * NT; i += 384) {
    int c = i / NT, t = i - c * NT;
    float2 m = mxs[((size_t)(b * NCHN + c) * NFREQ + f) * NT + t];
    float w = Wsh[t];
    MWsh[c][t] = make_float2(w * m.x, -w * m.y);
  }
  __syncthreads();

  const float invT = 1.0f / (float)NT;
  if (tid < TAPS * (TAPS + 1) / 2) {
    // lower-triangle pair (p >= q)
    int p = (int)((sqrtf(8.0f * (float)tid + 1.0f) - 1.0f) * 0.5f);
    while ((p + 1) * (p + 2) / 2 <= tid) ++p;
    while (p * (p + 1) / 2 > tid) --p;
    int q = tid - p * (p + 1) / 2;
    int t0 = (TAPS - 1) - q;
    float ax = 0.0f, ay = 0.0f;
    for (int t = t0; t < NT; ++t) {
      float w = Wsh[t];
      float2 a = Ysh[t - (TAPS - 1) + p];
      float2 bb = Ysh[t - (TAPS - 1) + q];
      float rr = a.x * bb.x + a.y * bb.y;
      float ii = a.y * bb.x - a.x * bb.y;
      ax = fmaf(w, rr, ax);
      ay = fmaf(w, ii, ay);
    }
    ax *= invT; ay *= invT;
    R[(size_t)g * TAPS * TAPS + p * TAPS + q] = make_float2(ax, ay);
    R[(size_t)g * TAPS * TAPS + q * TAPS + p] = make_float2(ax, -ay);
  } else if (tid >= 256 && tid < 256 + TAPS * NCHN) {
    int i = tid - 256;
    int p = i / NCHN, c = i - p * NCHN;
    int t0 = (TAPS - 1) - p;
    float ax = 0.0f, ay = 0.0f;
    for (int t = t0; t < NT; ++t) {
      float2 a = Ysh[t - (TAPS - 1) + p];
      float2 mw = MWsh[c][t];
      ax += a.x * mw.x - a.y * mw.y;
      ay += a.x * mw.y + a.y * mw.x;
    }
    P[(size_t)g * TAPS * NCHN + i] = make_float2(ax * invT, ay * invT);
  }
}

// ---------------- LU solve with partial pivoting (complex128) ----------------
// Writes Re(conj G) = Re(G) as float32 to d_out[0:G_ELEMS]; full conj(G) to gct.
__global__ void solve_kernel(const float2* __restrict__ R, const float2* __restrict__ P,
                             float* __restrict__ gout, float2* __restrict__ gct) {
  __shared__ double2 A[TAPS][TAPS];
  __shared__ double2 Bm[TAPS][NCHN];
  __shared__ int piv;
  int g = blockIdx.x;
  int tid = threadIdx.x;
  int s = g & 1;
  int bf = g >> 1;
  int f = bf % NFREQ;
  int b = bf / NFREQ;
  int bs = b * NSPK + s;

  for (int i = tid; i < TAPS * TAPS; i += 64) {
    float2 r = R[(size_t)g * TAPS * TAPS + i];
    A[i / TAPS][i % TAPS] = make_double2((double)r.x, (double)r.y);
  }
  for (int i = tid; i < TAPS * NCHN; i += 64) {
    float2 p = P[(size_t)g * TAPS * NCHN + i];
    Bm[i / NCHN][i % NCHN] = make_double2((double)p.x, (double)p.y);
  }
  __syncthreads();
  if (tid < TAPS) A[tid][tid].x += LAMBDA_REG;
  __syncthreads();

  for (int k = 0; k < TAPS; ++k) {
    if (tid == 0) {
      int r = k;
      double best = fabs(A[k][k].x) + fabs(A[k][k].y);
      for (int i = k + 1; i < TAPS; ++i) {
        double v = fabs(A[i][k].x) + fabs(A[i][k].y);
        if (v > best) { best = v; r = i; }
      }
      piv = r;
    }
    __syncthreads();
    int r = piv;
    if (r != k) {
      if (tid < TAPS) {
        double2 tmp = A[k][tid]; A[k][tid] = A[r][tid]; A[r][tid] = tmp;
      } else if (tid < TAPS + NCHN) {
        int c = tid - TAPS;
        double2 tmp = Bm[k][c]; Bm[k][c] = Bm[r][c]; Bm[r][c] = tmp;
      }
    }
    __syncthreads();
    double2 akk = A[k][k];
    double den = akk.x * akk.x + akk.y * akk.y;
    if (tid > k && tid < TAPS) {
      double2 a = A[tid][k];  // a / akk = a*conj(akk)/den
      A[tid][k] = make_double2((a.x * akk.x + a.y * akk.y) / den,
                               (a.y * akk.x - a.x * akk.y) / den);
    }
    __syncthreads();
    int nr = TAPS - 1 - k;
    int nc = nr + NCHN;  // trailing A cols + B cols
    for (int idx = tid; idx < nr * nc; idx += 64) {
      int i = k + 1 + idx / nc;
      int jj = idx % nc;
      double2 mlt = A[i][k];
      if (jj < nr) {
        int j = k + 1 + jj;
        double2 u = A[k][j];
        A[i][j].x -= mlt.x * u.x - mlt.y * u.y;
        A[i][j].y -= mlt.x * u.y + mlt.y * u.x;
      } else {
        int c = jj - nr;
        double2 u = Bm[k][c];
        Bm[i][c].x -= mlt.x * u.x - mlt.y * u.y;
        Bm[i][c].y -= mlt.x * u.y + mlt.y * u.x;
      }
    }
    __syncthreads();
  }

  // back substitution U x = y
  if (tid < NCHN) {
    int c = tid;
    for (int k = TAPS - 1; k >= 0; --k) {
      double sx = Bm[k][c].x, sy = Bm[k][c].y;
      for (int j = k + 1; j < TAPS; ++j) {
        double2 u = A[k][j], xv = Bm[j][c];
        sx -= u.x * xv.x - u.y * xv.y;
        sy -= u.x * xv.y + u.y * xv.x;
      }
      double2 akk = A[k][k];
      double den = akk.x * akk.x + akk.y * akk.y;
      Bm[k][c] = make_double2((sx * akk.x + sy * akk.y) / den,
                              (sy * akk.x - sx * akk.y) / den);
    }
  }
  __syncthreads();

  for (int i = tid; i < TAPS * NCHN; i += 64) {
    int p = i / NCHN, c = i - p * NCHN;
    double2 gv = Bm[p][c];
    float gx = (float)gv.x, gy = (float)(-gv.y);  // conj(G)
    gout[(size_t)g * TAPS * NCHN + i] = gx;       // float32, real part only
    gct[(((size_t)bs * TAPS + p) * NCHN + c) * NFREQ + f] = make_float2(gx, gy);
  }
}

// ---------------- ret + inverse FFT (radix-2), 5 frames per block ----------------
// grid: NSIG * NCHUNK blocks, 256 threads. blk = sc*NCHUNK + chunk
// Stages gct[p][f] slab (41 KB) in LDS once, amortized over 5 frames.
__global__ void ret_ifft_kernel(const float2* __restrict__ spht, const float2* __restrict__ gct,
                                float* __restrict__ frames) {
  __shared__ float2 gcsh[TAPS][NFREQ];
  __shared__ float2 spec[NFREQ];
  __shared__ float2 buf[NFFT];
  int blk = blockIdx.x;
  int chunk = blk % NCHUNK;
  int sc = blk / NCHUNK;
  int c = sc % NCHN;
  int bs = sc / NCHN;
  int tid = threadIdx.x;
  int tbase = chunk * TCHUNK;

  for (int i = tid; i < TAPS * NFREQ; i += 256) {
    int p = i / NFREQ, f = i - p * NFREQ;
    gcsh[p][f] = gct[(((size_t)bs * TAPS + p) * NCHN + c) * NFREQ + f];
  }
  __syncthreads();

  for (int tt = 0; tt < TCHUNK; ++tt) {
    int t = tbase + tt;
    int p0 = max(0, (TAPS - 1) - t);
    for (int f = tid; f < NFREQ; f += 256) {
      float sx = 0.0f, sy = 0.0f;
      for (int p = p0; p < TAPS; ++p) {
        float2 y = spht[((size_t)bs * NT + (t - (TAPS - 1) + p)) * NFREQ + f];
        float2 gc = gcsh[p][f];
        sx += y.x * gc.x - y.y * gc.y;
        sy += y.x * gc.y + y.y * gc.x;
      }
      spec[f] = make_float2(sx, sy);
    }
    __syncthreads();
    // Hermitian extension into bit-reversed positions
    for (int k = tid; k < NFFT; k += 256) {
      float2 v;
      if (k <= NFFT / 2) v = spec[k];
      else {
        float2 u = spec[NFFT - k];
        v = make_float2(u.x, -u.y);
      }
      buf[rev9(k)] = v;
    }
    __syncthreads();
    fft512(buf, tid, +1.0f);

    float* frow = frames + ((size_t)sc * NT + t) * NFFT;
    for (int n = tid; n < NFFT; n += 256) {
      float w = sinf(PI_F * (float)n / (float)NFFT);
      frow[n] = buf[n].x * (1.0f / (float)NFFT) * w;
    }
    __syncthreads();  // protect buf/spec before next frame
  }
}

// ---------------- overlap-add + env normalize + crop (float32 out) ----------------
__global__ void ola_kernel(const float* __restrict__ frames, float* __restrict__ out) {
  int i = blockIdx.x * 256 + threadIdx.x;
  if (i >= NSIG * LSIG) return;
  int sig = i / LSIG;
  int l = i - sig * LSIG;
  int lp = l + NFFT / 2;
  int j0 = max(0, (lp - (NFFT - HOPSZ)) / HOPSZ);
  int j1 = min(NT - 1, lp / HOPSZ);
  float acc = 0.0f, env = 0.0f;
  for (int j = j0; j <= j1; ++j) {
    int n = lp - j * HOPSZ;
    acc += frames[((size_t)sig * NT + j) * NFFT + n];
    float w = sinf(PI_F * (float)n / (float)NFFT);
    env += w * w;
  }
  out[(size_t)G_ELEMS + i] = acc / (env > 1e-11f ? env : 1.0f);
}

}  // namespace

extern "C" void kernel_launch(void* const* d_in, const int* in_sizes, int n_in,
                              void* d_out, int out_size, void* d_ws, size_t ws_size,
                              hipStream_t stream) {
  const float* ref = (const float*)d_in[0];
  const float* mix = (const float*)d_in[1];
  if (n_in >= 2 && in_sizes[0] > in_sizes[1]) {
    const float* tmp = ref; ref = mix; mix = tmp;
  }
  char* ws = (char*)d_ws;

  float2*  sph   = (float2*)(ws + SPH_B);
  float2*  spht  = (float2*)(ws + SPHT_B);
  float2*  mxs   = (float2*)(ws + MXS_B);
  float*   power = (float*)(ws + POW_B);
  float*   mx    = (float*)(ws + MX_B);
  float2*  R     = (float2*)(ws + R_B);
  float2*  P     = (float2*)(ws + P_B);
  float2*  gct   = (float2*)(ws + GCT_B);
  float*   frames= (float*)(ws + FRM_B);
  float*   out   = (float*)d_out;

  stft_kernel<<<dim3((NB * NSPK + NB * NCHN) * NT), dim3(256), 0, stream>>>(ref, mix, sph, spht, mxs);
  power_kernel<<<dim3((NB * NFREQ * NT + 255) / 256), dim3(256), 0, stream>>>(mxs, power);
  max_kernel<<<dim3(NB), dim3(256), 0, stream>>>(power, mx);
  rp_kernel<<<dim3(NG), dim3(384), 0, stream>>>(sph, mxs, power, mx, R, P);
  solve_kernel<<<dim3(NG), dim3(64), 0, stream>>>(R, P, out, gct);
  ret_ifft_kernel<<<dim3(NSIG * NCHUNK), dim3(256), 0, stream>>>(spht, gct, frames);
  ola_kernel<<<dim3((NSIG * LSIG + 255) / 256), dim3(256), 0, stream>>>(frames, out);
}

// Round 8
// 520.306 us; speedup vs baseline: 4.7758x; 1.2549x over previous
//
#include <hip/hip_runtime.h>
#include <math.h>

namespace {

constexpr int NB = 4, NSPK = 2, NCHN = 6;
constexpr int LSIG = 64000;
constexpr int NFFT = 512, HOPSZ = 128, NFREQ = 257;
constexpr int NT = 505;               // frames
constexpr int TAPS = 20;
constexpr int NG = NB * NFREQ * NSPK; // 2056 systems
constexpr int NSIG = NB * NSPK * NCHN; // 48 istft signals
constexpr float PI_F = 3.14159265358979323846f;
constexpr double LAMBDA_REG = 2e-4;
constexpr float FCP_EPS_F = 1e-3f;
constexpr int G_ELEMS = NG * TAPS * NCHN; // 246720 floats (real part only)

constexpr size_t WS_ALIGN = 256;
constexpr size_t align_up(size_t x) { return (x + WS_ALIGN - 1) & ~(WS_ALIGN - 1); }

// ws byte offsets
constexpr size_t SPH_B  = 0;                                        // [8][257][505] float2
constexpr size_t SPH_SZ = (size_t)NB * NSPK * NFREQ * NT * 8;
constexpr size_t SPHT_B = align_up(SPH_B + SPH_SZ);                 // [8][505][257] float2
constexpr size_t MXS_B  = align_up(SPHT_B + SPH_SZ);                // [24][257][505] float2
constexpr size_t MXS_SZ = (size_t)NB * NCHN * NFREQ * NT * 8;
constexpr size_t POW_B  = align_up(MXS_B + MXS_SZ);                 // [4][257][505] float
constexpr size_t POW_SZ = (size_t)NB * NFREQ * NT * 4;
constexpr size_t MX_B   = align_up(POW_B + POW_SZ);                 // [4] float
constexpr size_t R_B    = align_up(MX_B + (size_t)NB * 4);          // [2056][400] float2
constexpr size_t R_SZ   = (size_t)NG * TAPS * TAPS * 8;
constexpr size_t P_B    = align_up(R_B + R_SZ);                     // [2056][120] float2
constexpr size_t P_SZ   = (size_t)NG * TAPS * NCHN * 8;
constexpr size_t GCT_B  = align_up(P_B + P_SZ);                     // [8][20][6][257] float2
constexpr size_t GCT_SZ = (size_t)NB * NSPK * TAPS * NCHN * NFREQ * 8;
constexpr size_t FRM_B  = align_up(GCT_B + GCT_SZ);                 // [48][505][512] float

__device__ __forceinline__ int rev9(int n) { return (int)(__brev((unsigned)n) >> 23); }

// In-LDS radix-2 DIT FFT, 512 points, 256 threads, input pre-bit-reversed.
// sign = -1 forward, +1 inverse (unscaled). HW-validated (r1 vs r2 bit-identical).
__device__ __forceinline__ void fft512(float2* buf, int tid, float sign) {
#pragma unroll
  for (int s = 1; s <= 9; ++s) {
    int half = 1 << (s - 1);
    int blk = tid >> (s - 1);
    int pos = tid & (half - 1);
    int i0 = (blk << s) + pos;
    int i1 = i0 + half;
    float ang = sign * 2.0f * PI_F * (float)pos / (float)(half << 1);
    float sn, cs;
    __sincosf(ang, &sn, &cs);
    float2 u = buf[i0];
    float2 v = buf[i1];
    float2 vw = make_float2(v.x * cs - v.y * sn, v.x * sn + v.y * cs);
    buf[i0] = make_float2(u.x + vw.x, u.y + vw.y);
    buf[i1] = make_float2(u.x - vw.x, u.y - vw.y);
    __syncthreads();
  }
}

// ---------------- STFT (radix-2 FFT) ----------------
// grid: (8 + 24) * NT blocks, 256 threads
__global__ void stft_kernel(const float* __restrict__ ref, const float* __restrict__ mix,
                            float2* __restrict__ sph, float2* __restrict__ spht,
                            float2* __restrict__ mxs) {
  __shared__ float2 buf[NFFT];
  int blk = blockIdx.x;
  int sig = blk / NT;
  int t = blk - sig * NT;
  int tid = threadIdx.x;
  bool is_ref = sig < NB * NSPK;
  int m = is_ref ? sig : (sig - NB * NSPK);
  const float* src = is_ref ? (ref + (size_t)m * LSIG) : (mix + (size_t)m * LSIG);

  for (int n = tid; n < NFFT; n += 256) {
    int g = t * HOPSZ + n - NFFT / 2;
    float v = (g >= 0 && g < LSIG) ? src[g] : 0.0f;
    float w = __sinf(PI_F * (float)n / (float)NFFT);  // sqrt-hann
    buf[rev9(n)] = make_float2(v * w, 0.0f);
  }
  __syncthreads();
  fft512(buf, tid, -1.0f);

  if (is_ref) {
    float2* d1 = sph + (size_t)m * NFREQ * NT;
    float2* d2 = spht + ((size_t)m * NT + t) * NFREQ;
    for (int f = tid; f < NFREQ; f += 256) {
      float2 v = buf[f];
      d1[(size_t)f * NT + t] = v;
      d2[f] = v;
    }
  } else {
    float2* d1 = mxs + (size_t)m * NFREQ * NT;
    for (int f = tid; f < NFREQ; f += 256) d1[(size_t)f * NT + t] = buf[f];
  }
}

// ---------------- power ----------------
__global__ void power_kernel(const float2* __restrict__ mxs, float* __restrict__ power) {
  int i = blockIdx.x * 256 + threadIdx.x;
  if (i >= NB * NFREQ * NT) return;
  int b = i / (NFREQ * NT);
  int r = i - b * (NFREQ * NT);
  float acc = 0.0f;
#pragma unroll
  for (int c = 0; c < NCHN; ++c) {
    float2 v = mxs[(size_t)(b * NCHN + c) * NFREQ * NT + r];
    acc += v.x * v.x + v.y * v.y;
  }
  power[i] = acc * (1.0f / (float)NCHN);
}

// ---------------- per-batch max ----------------
__global__ void max_kernel(const float* __restrict__ power, float* __restrict__ mx) {
  int b = blockIdx.x;
  const float* p = power + (size_t)b * NFREQ * NT;
  float m = 0.0f;
  for (int i = threadIdx.x; i < NFREQ * NT; i += 256) m = fmaxf(m, p[i]);
#pragma unroll
  for (int off = 32; off > 0; off >>= 1) m = fmaxf(m, __shfl_down(m, off, 64));
  __shared__ float sm[4];
  int wave = threadIdx.x >> 6, lane = threadIdx.x & 63;
  if (lane == 0) sm[wave] = m;
  __syncthreads();
  if (threadIdx.x == 0) mx[b] = fmaxf(fmaxf(sm[0], sm[1]), fmaxf(sm[2], sm[3]));
}

// ---------------- R / P accumulation (fp32, Hermitian R) ----------------
// grid: NG blocks, 384 threads (6 waves). Threads 0-209: R lower triangle.
// Threads 256-375: P. Matches reference's float32 einsum arithmetic.
__global__ void rp_kernel(const float2* __restrict__ sph, const float2* __restrict__ mxs,
                          const float* __restrict__ power, const float* __restrict__ mx,
                          float2* __restrict__ R, float2* __restrict__ P) {
  __shared__ float2 Ysh[NT];
  __shared__ float2 MWsh[NCHN][NT];   // w[t] * conj(M[c][t])
  __shared__ float Wsh[NT];
  int g = blockIdx.x;
  int s = g & 1;
  int bf = g >> 1;
  int f = bf % NFREQ;
  int b = bf / NFREQ;
  int tid = threadIdx.x;

  const float2* yrow = sph + ((size_t)(b * NSPK + s) * NFREQ + f) * NT;
  const float* prow = power + ((size_t)b * NFREQ + f) * NT;
  float add = mx[b] * FCP_EPS_F + 1e-6f;
  for (int t = tid; t < NT; t += 384) {
    Wsh[t] = 1.0f / (prow[t] + add);
    Ysh[t] = yrow[t];
  }
  __syncthreads();
  for (int i = tid; i < NCHN * NT; i += 384) {
    int c = i / NT, t = i - c * NT;
    float2 m = mxs[((size_t)(b * NCHN + c) * NFREQ + f) * NT + t];
    float w = Wsh[t];
    MWsh[c][t] = make_float2(w * m.x, -w * m.y);
  }
  __syncthreads();

  const float invT = 1.0f / (float)NT;
  if (tid < TAPS * (TAPS + 1) / 2) {
    // lower-triangle pair (p >= q)
    int p = (int)((sqrtf(8.0f * (float)tid + 1.0f) - 1.0f) * 0.5f);
    while ((p + 1) * (p + 2) / 2 <= tid) ++p;
    while (p * (p + 1) / 2 > tid) --p;
    int q = tid - p * (p + 1) / 2;
    int t0 = (TAPS - 1) - q;
    float ax = 0.0f, ay = 0.0f;
    for (int t = t0; t < NT; ++t) {
      float w = Wsh[t];
      float2 a = Ysh[t - (TAPS - 1) + p];
      float2 bb = Ysh[t - (TAPS - 1) + q];
      float rr = a.x * bb.x + a.y * bb.y;
      float ii = a.y * bb.x - a.x * bb.y;
      ax = fmaf(w, rr, ax);
      ay = fmaf(w, ii, ay);
    }
    ax *= invT; ay *= invT;
    R[(size_t)g * TAPS * TAPS + p * TAPS + q] = make_float2(ax, ay);
    R[(size_t)g * TAPS * TAPS + q * TAPS + p] = make_float2(ax, -ay);
  } else if (tid >= 256 && tid < 256 + TAPS * NCHN) {
    int i = tid - 256;
    int p = i / NCHN, c = i - p * NCHN;
    int t0 = (TAPS - 1) - p;
    float ax = 0.0f, ay = 0.0f;
    for (int t = t0; t < NT; ++t) {
      float2 a = Ysh[t - (TAPS - 1) + p];
      float2 mw = MWsh[c][t];
      ax += a.x * mw.x - a.y * mw.y;
      ay += a.x * mw.y + a.y * mw.x;
    }
    P[(size_t)g * TAPS * NCHN + i] = make_float2(ax * invT, ay * invT);
  }
}

// ---------------- LU solve with partial pivoting (complex128) ----------------
// Writes Re(conj G) = Re(G) as float32 to d_out[0:G_ELEMS]; full conj(G) to gct.
__global__ void solve_kernel(const float2* __restrict__ R, const float2* __restrict__ P,
                             float* __restrict__ gout, float2* __restrict__ gct) {
  __shared__ double2 A[TAPS][TAPS];
  __shared__ double2 Bm[TAPS][NCHN];
  __shared__ int piv;
  int g = blockIdx.x;
  int tid = threadIdx.x;
  int s = g & 1;
  int bf = g >> 1;
  int f = bf % NFREQ;
  int b = bf / NFREQ;
  int bs = b * NSPK + s;

  for (int i = tid; i < TAPS * TAPS; i += 64) {
    float2 r = R[(size_t)g * TAPS * TAPS + i];
    A[i / TAPS][i % TAPS] = make_double2((double)r.x, (double)r.y);
  }
  for (int i = tid; i < TAPS * NCHN; i += 64) {
    float2 p = P[(size_t)g * TAPS * NCHN + i];
    Bm[i / NCHN][i % NCHN] = make_double2((double)p.x, (double)p.y);
  }
  __syncthreads();
  if (tid < TAPS) A[tid][tid].x += LAMBDA_REG;
  __syncthreads();

  for (int k = 0; k < TAPS; ++k) {
    if (tid == 0) {
      int r = k;
      double best = fabs(A[k][k].x) + fabs(A[k][k].y);
      for (int i = k + 1; i < TAPS; ++i) {
        double v = fabs(A[i][k].x) + fabs(A[i][k].y);
        if (v > best) { best = v; r = i; }
      }
      piv = r;
    }
    __syncthreads();
    int r = piv;
    if (r != k) {
      if (tid < TAPS) {
        double2 tmp = A[k][tid]; A[k][tid] = A[r][tid]; A[r][tid] = tmp;
      } else if (tid < TAPS + NCHN) {
        int c = tid - TAPS;
        double2 tmp = Bm[k][c]; Bm[k][c] = Bm[r][c]; Bm[r][c] = tmp;
      }
    }
    __syncthreads();
    double2 akk = A[k][k];
    double den = akk.x * akk.x + akk.y * akk.y;
    if (tid > k && tid < TAPS) {
      double2 a = A[tid][k];  // a / akk = a*conj(akk)/den
      A[tid][k] = make_double2((a.x * akk.x + a.y * akk.y) / den,
                               (a.y * akk.x - a.x * akk.y) / den);
    }
    __syncthreads();
    int nr = TAPS - 1 - k;
    int nc = nr + NCHN;  // trailing A cols + B cols
    for (int idx = tid; idx < nr * nc; idx += 64) {
      int i = k + 1 + idx / nc;
      int jj = idx % nc;
      double2 mlt = A[i][k];
      if (jj < nr) {
        int j = k + 1 + jj;
        double2 u = A[k][j];
        A[i][j].x -= mlt.x * u.x - mlt.y * u.y;
        A[i][j].y -= mlt.x * u.y + mlt.y * u.x;
      } else {
        int c = jj - nr;
        double2 u = Bm[k][c];
        Bm[i][c].x -= mlt.x * u.x - mlt.y * u.y;
        Bm[i][c].y -= mlt.x * u.y + mlt.y * u.x;
      }
    }
    __syncthreads();
  }

  // back substitution U x = y
  if (tid < NCHN) {
    int c = tid;
    for (int k = TAPS - 1; k >= 0; --k) {
      double sx = Bm[k][c].x, sy = Bm[k][c].y;
      for (int j = k + 1; j < TAPS; ++j) {
        double2 u = A[k][j], xv = Bm[j][c];
        sx -= u.x * xv.x - u.y * xv.y;
        sy -= u.x * xv.y + u.y * xv.x;
      }
      double2 akk = A[k][k];
      double den = akk.x * akk.x + akk.y * akk.y;
      Bm[k][c] = make_double2((sx * akk.x + sy * akk.y) / den,
                              (sy * akk.x - sx * akk.y) / den);
    }
  }
  __syncthreads();

  for (int i = tid; i < TAPS * NCHN; i += 64) {
    int p = i / NCHN, c = i - p * NCHN;
    double2 gv = Bm[p][c];
    float gx = (float)gv.x, gy = (float)(-gv.y);  // conj(G)
    gout[(size_t)g * TAPS * NCHN + i] = gx;       // float32, real part only
    gct[(((size_t)bs * TAPS + p) * NCHN + c) * NFREQ + f] = make_float2(gx, gy);
  }
}

// ---------------- ret + inverse FFT (radix-2), one frame per block ----------------
// grid: NSIG*NT blocks, 256 threads. blk = sc*NT + t, sc = (b*2+s)*6+c
// Hermitian extension fused into the spec pass (register scatter, no spec array).
__global__ void ret_ifft_kernel(const float2* __restrict__ spht, const float2* __restrict__ gct,
                                float* __restrict__ frames) {
  __shared__ float2 buf[NFFT];
  int blk = blockIdx.x;
  int t = blk % NT;
  int sc = blk / NT;
  int c = sc % NCHN;
  int bs = sc / NCHN;
  int tid = threadIdx.x;

  int p0 = max(0, (TAPS - 1) - t);
  const float2* ybase = spht + ((size_t)bs * NT + (t - (TAPS - 1))) * NFREQ;
  const float2* gbase = gct + ((size_t)bs * TAPS * NCHN + c) * NFREQ;
  for (int f = tid; f < NFREQ; f += 256) {
    float sx = 0.0f, sy = 0.0f;
    for (int p = p0; p < TAPS; ++p) {
      float2 y = ybase[(size_t)p * NFREQ + f];
      float2 gc = gbase[(size_t)p * NCHN * NFREQ + f];
      sx += y.x * gc.x - y.y * gc.y;
      sy += y.x * gc.y + y.y * gc.x;
    }
    buf[rev9(f)] = make_float2(sx, sy);
    if (f > 0 && f < NFFT / 2) buf[rev9(NFFT - f)] = make_float2(sx, -sy);
  }
  __syncthreads();
  fft512(buf, tid, +1.0f);

  float* frow = frames + ((size_t)sc * NT + t) * NFFT;
  for (int n = tid; n < NFFT; n += 256) {
    float w = __sinf(PI_F * (float)n / (float)NFFT);
    frow[n] = buf[n].x * (1.0f / (float)NFFT) * w;
  }
}

// ---------------- overlap-add + env normalize + crop (float32 out) ----------------
__global__ void ola_kernel(const float* __restrict__ frames, float* __restrict__ out) {
  int i = blockIdx.x * 256 + threadIdx.x;
  if (i >= NSIG * LSIG) return;
  int sig = i / LSIG;
  int l = i - sig * LSIG;
  int lp = l + NFFT / 2;
  int j0 = max(0, (lp - (NFFT - HOPSZ)) / HOPSZ);
  int j1 = min(NT - 1, lp / HOPSZ);
  float acc = 0.0f, env = 0.0f;
  for (int j = j0; j <= j1; ++j) {
    int n = lp - j * HOPSZ;
    acc += frames[((size_t)sig * NT + j) * NFFT + n];
    float w = __sinf(PI_F * (float)n / (float)NFFT);
    env += w * w;
  }
  out[(size_t)G_ELEMS + i] = acc / (env > 1e-11f ? env : 1.0f);
}

}  // namespace

extern "C" void kernel_launch(void* const* d_in, const int* in_sizes, int n_in,
                              void* d_out, int out_size, void* d_ws, size_t ws_size,
                              hipStream_t stream) {
  const float* ref = (const float*)d_in[0];
  const float* mix = (const float*)d_in[1];
  if (n_in >= 2 && in_sizes[0] > in_sizes[1]) {
    const float* tmp = ref; ref = mix; mix = tmp;
  }
  char* ws = (char*)d_ws;

  float2*  sph   = (float2*)(ws + SPH_B);
  float2*  spht  = (float2*)(ws + SPHT_B);
  float2*  mxs   = (float2*)(ws + MXS_B);
  float*   power = (float*)(ws + POW_B);
  float*   mx    = (float*)(ws + MX_B);
  float2*  R     = (float2*)(ws + R_B);
  float2*  P     = (float2*)(ws + P_B);
  float2*  gct   = (float2*)(ws + GCT_B);
  float*   frames= (float*)(ws + FRM_B);
  float*   out   = (float*)d_out;

  stft_kernel<<<dim3((NB * NSPK + NB * NCHN) * NT), dim3(256), 0, stream>>>(ref, mix, sph, spht, mxs);
  power_kernel<<<dim3((NB * NFREQ * NT + 255) / 256), dim3(256), 0, stream>>>(mxs, power);
  max_kernel<<<dim3(NB), dim3(256), 0, stream>>>(power, mx);
  rp_kernel<<<dim3(NG), dim3(384), 0, stream>>>(sph, mxs, power, mx, R, P);
  solve_kernel<<<dim3(NG), dim3(64), 0, stream>>>(R, P, out, gct);
  ret_ifft_kernel<<<dim3(NSIG * NT), dim3(256), 0, stream>>>(spht, gct, frames);
  ola_kernel<<<dim3((NSIG * LSIG + 255) / 256), dim3(256), 0, stream>>>(frames, out);
}